// Round 5
// baseline (489.144 us; speedup 1.0000x reference)
//
#include <hip/hip_runtime.h>
#include <hip/hip_bf16.h>
#include <math.h>

#define NCLS 20
#define KDIM 128
#define ALPHA 0.7f
#define BETA 1.5f

// ws layout (floats): [0, NCLS*KDIM) class sums; [NCLS*KDIM, +NCLS) counts;
// [WS_INTRA, +NCLS) intra partials; [WS_AB, +8) ablation sinks.
#define WS_SUMS 0
#define WS_CNT (NCLS * KDIM)
#define WS_INTRA (NCLS * KDIM + NCLS)
#define WS_TOTAL (NCLS * KDIM + 2 * NCLS)
#define WS_AB WS_TOTAL
#define WS_FULL (WS_TOTAL + 8)

__global__ void k_init(float* ws) {
    int i = blockIdx.x * blockDim.x + threadIdx.x;
    if (i < WS_FULL) ws[i] = 0.0f;
}

#define SUMS_BLK 128
#define SUMS_GRID 2048

// ---------- ABLATION A: chunked float2 loads, iso-LDS with k_sums, NO scatter ----------
__global__ void __launch_bounds__(SUMS_BLK) k_ab_load2c(const float2* __restrict__ emb2,
                                                        float* __restrict__ ws, int N) {
    __shared__ float lsum[2][NCLS * KDIM];  // dummy, keeps occupancy identical to k_sums
    const int tid = threadIdx.x;
    const int w = tid >> 6, k = tid & 63;
    const int chunk = blockIdx.x * SUMS_BLK;
    const int npts = min(SUMS_BLK, N - chunk);
    float sx = 0.f, sy = 0.f;
#pragma unroll 4
    for (int pl = w; pl < npts; pl += 2) {
        const float2 v = emb2[(size_t)(chunk + pl) * 64 + k];
        sx += v.x; sy += v.y;
    }
    lsum[0][tid] = sx;
    lsum[1][tid] = sy;
    __syncthreads();
    if (tid == 0) {
        float s = 0.f;
        for (int i = 0; i < SUMS_BLK; i++) s += lsum[0][i] + lsum[1][i];
        unsafeAtomicAdd(&ws[WS_AB + 0], s);
    }
}

// ---------- ABLATION B: strided float2 loads, no LDS, no scatter ----------
__global__ void __launch_bounds__(256) k_ab_load2s(const float2* __restrict__ emb2,
                                                   float* __restrict__ ws, int N) {
    const int tid = threadIdx.x;
    const int lane = tid & 63;
    const int gw = blockIdx.x * 4 + (tid >> 6);
    const int wstride = 2048 * 4;
    float s = 0.f;
#pragma unroll 4
    for (int p = gw; p < N; p += wstride) {
        const float2 v = emb2[(size_t)p * 64 + lane];
        s += v.x + v.y;
    }
    for (int off = 32; off >= 1; off >>= 1) s += __shfl_down(s, off, 64);
    if (lane == 0) unsafeAtomicAdd(&ws[WS_AB + 1], s);
}

// ---------- ABLATION C: strided float4 loads (k_intra shape), no LDS, no scatter ----------
__global__ void __launch_bounds__(256) k_ab_load4s(const float4* __restrict__ emb4,
                                                   float* __restrict__ ws, int N) {
    const int tid = threadIdx.x;
    const int s32 = tid & 31;
    const int pp = tid >> 5;
    const int stride = 2048 * 8;
    float s = 0.f;
#pragma unroll 2
    for (int p = blockIdx.x * 8 + pp; p < N; p += stride) {
        const float4 v = emb4[(size_t)p * 32 + s32];
        s += v.x + v.y + v.z + v.w;
    }
    for (int off = 32; off >= 1; off >>= 1) s += __shfl_down(s, off, 64);
    if ((tid & 63) == 0) unsafeAtomicAdd(&ws[WS_AB + 2], s);
}

// ---------- ABLATION D: exact R4 k_sums (load + LDS scatter RMW), sink flush ----------
__global__ void __launch_bounds__(SUMS_BLK) k_ab_r4(const float2* __restrict__ emb2,
                                                    const int* __restrict__ t,
                                                    float* __restrict__ ws, int N) {
    __shared__ float lsum[2][NCLS * KDIM];
    __shared__ int lds_t[SUMS_BLK];
    const int tid = threadIdx.x;
    const int w = tid >> 6, k = tid & 63;
    for (int i = tid; i < 2 * NCLS * KDIM; i += SUMS_BLK) (&lsum[0][0])[i] = 0.0f;
    const int chunk = blockIdx.x * SUMS_BLK;
    const int npts = min(SUMS_BLK, N - chunk);
    if (tid < npts) lds_t[tid] = t[chunk + tid];
    __syncthreads();
    float* myLsum = lsum[w];
#pragma unroll 4
    for (int pl = w; pl < npts; pl += 2) {
        const int c = lds_t[pl];
        const float2 v = emb2[(size_t)(chunk + pl) * 64 + k];
        float* a = &myLsum[c * KDIM + 2 * k];
        a[0] += v.x;
        a[1] += v.y;
    }
    __syncthreads();
    float s = 0.f;
    for (int i = tid; i < NCLS * KDIM; i += SUMS_BLK) s += lsum[0][i] + lsum[1][i];
    unsafeAtomicAdd(&ws[WS_AB + 3], s);  // sink (no real 2560-wide flush)
}

// ---------- REAL pass 1: R4 + 8-deep load batching ----------
__global__ void __launch_bounds__(SUMS_BLK) k_sums(const float2* __restrict__ emb2,
                                                   const int* __restrict__ t,
                                                   float* __restrict__ ws, int N) {
    __shared__ float lsum[2][NCLS * KDIM];
    __shared__ float lcnt[NCLS];
    __shared__ int lds_t[SUMS_BLK];
    const int tid = threadIdx.x;
    const int w = tid >> 6, k = tid & 63;
    for (int i = tid; i < 2 * NCLS * KDIM; i += SUMS_BLK) (&lsum[0][0])[i] = 0.0f;
    if (tid < NCLS) lcnt[tid] = 0.0f;
    __syncthreads();

    const int chunk = blockIdx.x * SUMS_BLK;
    const int npts = min(SUMS_BLK, N - chunk);
    if (tid < npts) {
        const int c = t[chunk + tid];
        lds_t[tid] = c;
        unsafeAtomicAdd(&lcnt[c], 1.0f);  // counts once, outside hot loop
    }
    __syncthreads();

    float* myLsum = lsum[w];
    if (npts == SUMS_BLK) {
        // 8 points per wave per batch: all 8 loads issued before any LDS RMW
        for (int m0 = 0; m0 < 64; m0 += 8) {
            float2 v0, v1, v2, v3, v4, v5, v6, v7;
            int c0, c1, c2, c3, c4, c5, c6, c7;
#define LD(j) { const int pl = w + 2 * (m0 + j); c##j = lds_t[pl]; \
                v##j = emb2[(size_t)(chunk + pl) * 64 + k]; }
            LD(0) LD(1) LD(2) LD(3) LD(4) LD(5) LD(6) LD(7)
#undef LD
#define ST(j) { float* a = &myLsum[c##j * KDIM + 2 * k]; a[0] += v##j.x; a[1] += v##j.y; }
            ST(0) ST(1) ST(2) ST(3) ST(4) ST(5) ST(6) ST(7)
#undef ST
        }
    } else {
        for (int pl = w; pl < npts; pl += 2) {
            const int c = lds_t[pl];
            const float2 v = emb2[(size_t)(chunk + pl) * 64 + k];
            float* a = &myLsum[c * KDIM + 2 * k];
            a[0] += v.x;
            a[1] += v.y;
        }
    }
    __syncthreads();

    for (int i = tid; i < NCLS * KDIM; i += SUMS_BLK)
        unsafeAtomicAdd(&ws[WS_SUMS + i], lsum[0][i] + lsum[1][i]);
    if (tid < NCLS) unsafeAtomicAdd(&ws[WS_CNT + tid], lcnt[tid]);
}

// ---------- pass 2 (unchanged, proven ~25us) ----------
#define GRID 2048
__global__ void __launch_bounds__(256) k_intra(const float4* __restrict__ emb4,
                                               const int* __restrict__ t,
                                               const float* __restrict__ pts,
                                               float* __restrict__ ws, int N) {
    __shared__ float lmean[NCLS * KDIM];
    __shared__ float lintra[NCLS];
    const int tid = threadIdx.x;
    for (int i = tid; i < NCLS * KDIM; i += 256) {
        float cnt = ws[WS_CNT + i / KDIM];
        lmean[i] = ws[WS_SUMS + i] / fmaxf(cnt, 1.0f);
    }
    if (tid < NCLS) lintra[tid] = 0.0f;
    __syncthreads();

    const int s = tid & 31;
    const int pp = tid >> 5;
    const int stride = GRID * 8;
    for (int p = blockIdx.x * 8 + pp; p < N; p += 2 * stride) {
        const int p1 = p + stride;
        {
            const int c = t[p];
            const float4 v = emb4[(size_t)p * 32 + s];
            const float4 m = *(const float4*)&lmean[c * KDIM + 4 * s];
            float dx = v.x - m.x, dy = v.y - m.y, dz = v.z - m.z, dw = v.w - m.w;
            float d2 = dx * dx + dy * dy + dz * dz + dw * dw;
            for (int off = 16; off >= 1; off >>= 1) d2 += __shfl_down(d2, off, 32);
            if (s == 0) {
                float d = sqrtf(d2);
                float px = pts[(size_t)p * 3 + 0];
                float py = pts[(size_t)p * 3 + 1];
                float pz = pts[(size_t)p * 3 + 2];
                float r = sqrtf(px * px + py * py + pz * pz);
                float g = 1.0f / (1.0f + expf(-r));
                float h = fmaxf(d - ALPHA, 0.0f);
                unsafeAtomicAdd(&lintra[c], g * h * h);
            }
        }
        if (p1 < N) {
            const int c = t[p1];
            const float4 v = emb4[(size_t)p1 * 32 + s];
            const float4 m = *(const float4*)&lmean[c * KDIM + 4 * s];
            float dx = v.x - m.x, dy = v.y - m.y, dz = v.z - m.z, dw = v.w - m.w;
            float d2 = dx * dx + dy * dy + dz * dz + dw * dw;
            for (int off = 16; off >= 1; off >>= 1) d2 += __shfl_down(d2, off, 32);
            if (s == 0) {
                float d = sqrtf(d2);
                float px = pts[(size_t)p1 * 3 + 0];
                float py = pts[(size_t)p1 * 3 + 1];
                float pz = pts[(size_t)p1 * 3 + 2];
                float r = sqrtf(px * px + py * py + pz * pz);
                float g = 1.0f / (1.0f + expf(-r));
                float h = fmaxf(d - ALPHA, 0.0f);
                unsafeAtomicAdd(&lintra[c], g * h * h);
            }
        }
    }
    __syncthreads();
    if (tid < NCLS) unsafeAtomicAdd(&ws[WS_INTRA + tid], lintra[tid]);
}

// ---------- final (unchanged) ----------
__global__ void __launch_bounds__(256) k_final(const float* __restrict__ ws,
                                               float* __restrict__ out) {
    __shared__ float lmean[NCLS * KDIM];
    __shared__ float red[256];
    const int tid = threadIdx.x;
    for (int i = tid; i < NCLS * KDIM; i += 256) {
        float cnt = ws[WS_CNT + i / KDIM];
        lmean[i] = ws[WS_SUMS + i] / fmaxf(cnt, 1.0f);
    }
    __syncthreads();

    float acc = 0.0f;
    for (int idx = tid; idx < 361; idx += 256) {
        int i = idx / 19 + 1;
        int j = idx % 19 + 1;
        if (i != j) {
            float sq = 0.0f;
            const float* mi = lmean + i * KDIM;
            const float* mj = lmean + j * KDIM;
            for (int k = 0; k < KDIM; k++) {
                float df = mi[k] - mj[k];
                sq += df * df;
            }
            float dist = sqrtf(sq);
            float h = fmaxf(BETA - dist, 0.0f);
            acc += h * h;
        }
    }
    red[tid] = acc;
    __syncthreads();
    for (int st = 128; st >= 1; st >>= 1) {
        if (tid < st) red[tid] += red[tid + st];
        __syncthreads();
    }
    if (tid == 0) {
        float intra = 0.0f;
        for (int c = 1; c < NCLS; c++) {
            intra += ws[WS_INTRA + c] / fmaxf(ws[WS_CNT + c], 1.0f);
        }
        out[0] = intra / (float)NCLS + red[0] / (float)(NCLS * (NCLS - 1));
    }
}

extern "C" void kernel_launch(void* const* d_in, const int* in_sizes, int n_in,
                              void* d_out, int out_size, void* d_ws, size_t ws_size,
                              hipStream_t stream) {
    const float* pts = (const float*)d_in[0];
    const int* t = (const int*)d_in[1];
    const float2* emb2 = (const float2*)d_in[2];
    const float4* emb4 = (const float4*)d_in[2];
    float* out = (float*)d_out;
    float* ws = (float*)d_ws;
    const int N = in_sizes[1];

    k_init<<<(WS_FULL + 255) / 256, 256, 0, stream>>>(ws);

    // diagnostic dispatches (profiled individually; outputs go to sinks)
    if (ws_size >= WS_FULL * sizeof(float)) {
        k_ab_load2c<<<SUMS_GRID, SUMS_BLK, 0, stream>>>(emb2, ws, N);
        k_ab_load2s<<<2048, 256, 0, stream>>>(emb2, ws, N);
        k_ab_load4s<<<2048, 256, 0, stream>>>(emb4, ws, N);
        k_ab_r4<<<SUMS_GRID, SUMS_BLK, 0, stream>>>(emb2, t, ws, N);
    }

    // real pipeline
    k_sums<<<SUMS_GRID, SUMS_BLK, 0, stream>>>(emb2, t, ws, N);
    k_intra<<<GRID, 256, 0, stream>>>(emb4, t, pts, ws, N);
    k_final<<<1, 256, 0, stream>>>(ws, out);
}

// Round 6
// 138.575 us; speedup vs baseline: 3.5298x; 3.5298x over previous
//
#include <hip/hip_runtime.h>
#include <hip/hip_bf16.h>
#include <math.h>

#define NCLS 20
#define KDIM 128
#define ALPHA 0.7f
#define BETA 1.5f

// ws layout (floats): [0, NCLS*KDIM) class sums; [NCLS*KDIM, +NCLS) counts;
//                     [WS_INTRA, +NCLS) intra partials
#define WS_SUMS 0
#define WS_CNT (NCLS * KDIM)
#define WS_INTRA (NCLS * KDIM + NCLS)
#define WS_TOTAL (NCLS * KDIM + 2 * NCLS)

__global__ void k_init(float* ws) {
    int i = blockIdx.x * blockDim.x + threadIdx.x;
    if (i < WS_TOTAL) ws[i] = 0.0f;
}

// Pass 1: per-class embedding sums + counts.
// R5 ablation verdict: 8B/lane loads are the wall (~1.1 TB/s); 16B/lane hit
// ~5 TB/s. So: wave loads a PAIR of consecutive points as one 1KB dwordx4
// (lanes 0-31 = p0 dims 4k..4k+3, lanes 32-63 = p1). Non-atomic RMW into a
// per-wave LDS copy; halves hit different class rows unless c0==c1 (~5%,
// scalar-uniform): then shfl_xor(32) pre-combines and only half 0 writes.
#define SUMS_BLK 128   // 2 waves
#define SUMS_GRID 2048 // 2048 * 128 = 262144 points

__global__ void __launch_bounds__(SUMS_BLK) k_sums(const float4* __restrict__ emb4,
                                                   const int* __restrict__ t,
                                                   float* __restrict__ ws, int N) {
    __shared__ float lsum[2][NCLS * KDIM];   // one copy per wave
    __shared__ float lcnt[NCLS];
    __shared__ int lds_t[SUMS_BLK];
    const int tid = threadIdx.x;
    const int w = tid >> 6;      // wave 0/1
    const int k = tid & 63;      // lane
    const int half = k >> 5;     // 0: lanes 0-31, 1: lanes 32-63
    const int k31 = k & 31;

    for (int i = tid; i < 2 * NCLS * KDIM; i += SUMS_BLK) (&lsum[0][0])[i] = 0.0f;
    if (tid < NCLS) lcnt[tid] = 0.0f;
    __syncthreads();

    const int chunk = blockIdx.x * SUMS_BLK;
    const int npts = min(SUMS_BLK, N - chunk);
    if (tid < npts) {
        const int c = t[chunk + tid];
        lds_t[tid] = c;
        unsafeAtomicAdd(&lcnt[c], 1.0f);   // counts once per block, outside hot loop
    }
    __syncthreads();

    float* myLsum = lsum[w];

    if (npts == SUMS_BLK) {
        // wave w owns pairs q in [32w, 32w+32); pair q = points (chunk+2q, +1)
        for (int qb = 32 * w; qb < 32 * w + 32; qb += 8) {
            float4 v0, v1, v2, v3, v4, v5, v6, v7;
#define LD(j) v##j = emb4[(size_t)(chunk + 2 * (qb + j)) * 32 + k];
            LD(0) LD(1) LD(2) LD(3) LD(4) LD(5) LD(6) LD(7)
#undef LD
#define ST(j) {                                                              \
    const int c0 = __builtin_amdgcn_readfirstlane(lds_t[2 * (qb + j)]);      \
    const int c1 = __builtin_amdgcn_readfirstlane(lds_t[2 * (qb + j) + 1]);  \
    float4 v = v##j;                                                         \
    if (c0 == c1) {                                                          \
        float4 vv;                                                           \
        vv.x = v.x + __shfl_xor(v.x, 32, 64);                                \
        vv.y = v.y + __shfl_xor(v.y, 32, 64);                                \
        vv.z = v.z + __shfl_xor(v.z, 32, 64);                                \
        vv.w = v.w + __shfl_xor(v.w, 32, 64);                                \
        if (half == 0) {                                                     \
            float4* a = (float4*)&myLsum[c0 * KDIM + 4 * k31];               \
            float4 o = *a;                                                   \
            o.x += vv.x; o.y += vv.y; o.z += vv.z; o.w += vv.w;              \
            *a = o;                                                          \
        }                                                                    \
    } else {                                                                 \
        const int c = half ? c1 : c0;                                        \
        float4* a = (float4*)&myLsum[c * KDIM + 4 * k31];                    \
        float4 o = *a;                                                       \
        o.x += v.x; o.y += v.y; o.z += v.z; o.w += v.w;                      \
        *a = o;                                                              \
    }                                                                        \
}
            ST(0) ST(1) ST(2) ST(3) ST(4) ST(5) ST(6) ST(7)
#undef ST
        }
    } else {
        // tail chunk (not hit for N=262144, kept for generality)
        for (int q = 32 * w; q < 32 * w + 32; q++) {
            const int p = chunk + 2 * q + half;
            if (p < N) {
                const int c = lds_t[2 * q + half];
                const float4 v = emb4[(size_t)p * 32 + (size_t)k31 +
                                      (size_t)half * 0];  // same addressing
                // serialize halves to avoid same-class pair race
                for (int h = 0; h < 2; h++) {
                    if (half == h) {
                        float4* a = (float4*)&myLsum[c * KDIM + 4 * k31];
                        float4 o = *a;
                        o.x += v.x; o.y += v.y; o.z += v.z; o.w += v.w;
                        *a = o;
                    }
                    __syncthreads();
                }
            }
        }
    }
    __syncthreads();

    for (int i = tid; i < NCLS * KDIM; i += SUMS_BLK)
        unsafeAtomicAdd(&ws[WS_SUMS + i], lsum[0][i] + lsum[1][i]);
    if (tid < NCLS) unsafeAtomicAdd(&ws[WS_CNT + tid], lcnt[tid]);
}

// Pass 2: per-point distance to own-class mean, gated hinge^2, per-class sums.
// (unchanged -- proven ~25-30us, float4 strided)
#define GRID 2048
__global__ void __launch_bounds__(256) k_intra(const float4* __restrict__ emb4,
                                               const int* __restrict__ t,
                                               const float* __restrict__ pts,
                                               float* __restrict__ ws, int N) {
    __shared__ float lmean[NCLS * KDIM];
    __shared__ float lintra[NCLS];
    const int tid = threadIdx.x;
    for (int i = tid; i < NCLS * KDIM; i += 256) {
        float cnt = ws[WS_CNT + i / KDIM];
        lmean[i] = ws[WS_SUMS + i] / fmaxf(cnt, 1.0f);
    }
    if (tid < NCLS) lintra[tid] = 0.0f;
    __syncthreads();

    const int s = tid & 31;
    const int pp = tid >> 5;
    const int stride = GRID * 8;
    for (int p = blockIdx.x * 8 + pp; p < N; p += 2 * stride) {
        const int p1 = p + stride;
        {
            const int c = t[p];
            const float4 v = emb4[(size_t)p * 32 + s];
            const float4 m = *(const float4*)&lmean[c * KDIM + 4 * s];
            float dx = v.x - m.x, dy = v.y - m.y, dz = v.z - m.z, dw = v.w - m.w;
            float d2 = dx * dx + dy * dy + dz * dz + dw * dw;
            for (int off = 16; off >= 1; off >>= 1) d2 += __shfl_down(d2, off, 32);
            if (s == 0) {
                float d = sqrtf(d2);
                float px = pts[(size_t)p * 3 + 0];
                float py = pts[(size_t)p * 3 + 1];
                float pz = pts[(size_t)p * 3 + 2];
                float r = sqrtf(px * px + py * py + pz * pz);
                float g = 1.0f / (1.0f + expf(-r));
                float h = fmaxf(d - ALPHA, 0.0f);
                unsafeAtomicAdd(&lintra[c], g * h * h);
            }
        }
        if (p1 < N) {
            const int c = t[p1];
            const float4 v = emb4[(size_t)p1 * 32 + s];
            const float4 m = *(const float4*)&lmean[c * KDIM + 4 * s];
            float dx = v.x - m.x, dy = v.y - m.y, dz = v.z - m.z, dw = v.w - m.w;
            float d2 = dx * dx + dy * dy + dz * dz + dw * dw;
            for (int off = 16; off >= 1; off >>= 1) d2 += __shfl_down(d2, off, 32);
            if (s == 0) {
                float d = sqrtf(d2);
                float px = pts[(size_t)p1 * 3 + 0];
                float py = pts[(size_t)p1 * 3 + 1];
                float pz = pts[(size_t)p1 * 3 + 2];
                float r = sqrtf(px * px + py * py + pz * pz);
                float g = 1.0f / (1.0f + expf(-r));
                float h = fmaxf(d - ALPHA, 0.0f);
                unsafeAtomicAdd(&lintra[c], g * h * h);
            }
        }
    }
    __syncthreads();
    if (tid < NCLS) unsafeAtomicAdd(&ws[WS_INTRA + tid], lintra[tid]);
}

// Final: intra (clusters 1..19) + inter over 19x19 pair matrix -> scalar.
__global__ void __launch_bounds__(256) k_final(const float* __restrict__ ws,
                                               float* __restrict__ out) {
    __shared__ float lmean[NCLS * KDIM];
    __shared__ float red[256];
    const int tid = threadIdx.x;
    for (int i = tid; i < NCLS * KDIM; i += 256) {
        float cnt = ws[WS_CNT + i / KDIM];
        lmean[i] = ws[WS_SUMS + i] / fmaxf(cnt, 1.0f);
    }
    __syncthreads();

    float acc = 0.0f;
    for (int idx = tid; idx < 361; idx += 256) {
        int i = idx / 19 + 1;
        int j = idx % 19 + 1;
        if (i != j) {
            float sq = 0.0f;
            const float* mi = lmean + i * KDIM;
            const float* mj = lmean + j * KDIM;
            for (int k = 0; k < KDIM; k++) {
                float df = mi[k] - mj[k];
                sq += df * df;
            }
            float dist = sqrtf(sq);
            float h = fmaxf(BETA - dist, 0.0f);
            acc += h * h;
        }
    }
    red[tid] = acc;
    __syncthreads();
    for (int st = 128; st >= 1; st >>= 1) {
        if (tid < st) red[tid] += red[tid + st];
        __syncthreads();
    }
    if (tid == 0) {
        float intra = 0.0f;
        for (int c = 1; c < NCLS; c++) {
            intra += ws[WS_INTRA + c] / fmaxf(ws[WS_CNT + c], 1.0f);
        }
        out[0] = intra / (float)NCLS + red[0] / (float)(NCLS * (NCLS - 1));
    }
}

extern "C" void kernel_launch(void* const* d_in, const int* in_sizes, int n_in,
                              void* d_out, int out_size, void* d_ws, size_t ws_size,
                              hipStream_t stream) {
    const float* pts = (const float*)d_in[0];
    const int* t = (const int*)d_in[1];
    const float4* emb4 = (const float4*)d_in[2];
    float* out = (float*)d_out;
    float* ws = (float*)d_ws;
    const int N = in_sizes[1];

    k_init<<<(WS_TOTAL + 255) / 256, 256, 0, stream>>>(ws);
    k_sums<<<SUMS_GRID, SUMS_BLK, 0, stream>>>(emb4, t, ws, N);
    k_intra<<<GRID, 256, 0, stream>>>(emb4, t, pts, ws, N);
    k_final<<<1, 256, 0, stream>>>(ws, out);
}